// Round 14
// baseline (31.145 us; speedup 1.0000x reference)
//
#include <hip/hip_runtime.h>

#define DI __device__ __forceinline__

constexpr int BATCH = 256;
constexpr int INF   = 4096;   // in_features
constexpr int NGRP  = 1024;   // INF/4
constexpr int MOUT  = 4096;   // out_features

using bf16x8 = __attribute__((ext_vector_type(8))) short;
using f32x4  = __attribute__((ext_vector_type(4))) float;

// D4 half-codebook, stored as 2x the actual values (int8); actual = v * 0.5
__device__ __constant__ signed char D4_I8[512] = {
     0, 0, 0, 0,  -4, 0, 0, 0,  -2,-2,-2,-2,  -2,-2,-2, 0,  -2,-2,-2, 2,  -2,-2, 0,-2,  -2,-2, 0, 0,  -2,-2, 0, 2,
    -2,-2, 2,-2,  -2,-2, 2, 0,  -2,-2, 2, 2,  -2, 0,-2,-2,  -2, 0,-2, 0,  -2, 0,-2, 2,  -2, 0, 0,-2,  -2, 0, 0, 0,
    -2, 0, 0, 2,  -2, 0, 2,-2,  -2, 0, 2, 0,  -2, 0, 2, 2,  -2, 2,-2,-2,  -2, 2,-2, 0,  -2, 2,-2, 2,  -2, 2, 0,-2,
    -2, 2, 0, 0,  -2, 2, 0, 2,  -2, 2, 2,-2,  -2, 2, 2, 0,  -2, 2, 2, 2,   0,-4, 0, 0,   0,-2,-2,-2,   0,-2,-2, 0,
     0,-2,-2, 2,   0,-2, 0,-2,   0,-2, 0, 0,   0,-2, 0, 2,   0,-2, 2,-2,   0,-2, 2, 0,   0,-2, 2, 2,   0, 0,-4, 0,
     0, 0,-2,-2,   0, 0,-2, 0,   0, 0,-2, 2,   0, 0, 0,-4,   0, 0, 0,-2,
    -3,-1,-3,-1,  -3,-1,-3, 1,  -3,-1,-1,-3,  -3,-1,-1,-1,  -3,-1,-1, 1,  -3,-1,-1, 3,  -3,-1, 1,-3,  -3,-1, 1,-1,
    -3,-1, 1, 1,  -3,-1, 1, 3,  -3,-1, 3,-1,  -3,-1, 3, 1,  -3, 1,-3,-1,  -3, 1,-3, 1,  -3, 1,-1,-3,  -3, 1,-1,-1,
    -3, 1,-1, 1,  -3, 1,-1, 3,  -3, 1, 1,-3,  -3, 1, 1,-1,  -3, 1, 1, 1,  -3, 1, 1, 3,  -3, 1, 3,-1,  -3, 1, 3, 1,
    -3, 3,-1,-1,  -3, 3, 1,-1,  -3, 3, 1, 1,  -1,-3,-3,-1,  -1,-3,-3, 1,  -1,-3,-1,-3,  -1,-3,-1,-1,  -1,-3,-1, 1,
    -1,-3,-1, 3,  -1,-3, 1,-3,  -1,-3, 1,-1,  -1,-3, 1, 1,  -1,-3, 1, 3,  -1,-3, 3,-1,  -1,-3, 3, 1,  -1,-1,-3,-3,
    -1,-1,-3,-1,  -1,-1,-3, 1,  -1,-1,-3, 3,  -1,-1,-1,-3,  -1,-1,-1,-1,  -1,-1,-1, 1,  -1,-1,-1, 3,  -1,-1, 1,-3,
    -1,-1, 1,-1,  -1,-1, 1, 1,  -1,-1, 1, 3,  -1,-1, 3,-3,  -1,-1, 3,-1,  -1,-1, 3, 1,  -1,-1, 3, 3,  -1, 1,-3,-3,
    -1, 1,-3,-1,  -1, 1,-3, 1,  -1, 1,-3, 3,  -1, 1,-1,-3,  -1, 1,-1,-1,  -1, 1,-1, 1,  -1, 1,-1, 3,  -1, 1, 1,-3,
    -1, 1, 1,-1,  -1, 1, 1, 1,  -1, 1, 1, 3,  -1, 1, 3,-3,  -1, 1, 3,-1,  -1, 1, 3, 1,  -1, 1, 3, 3,  -1, 3,-3,-1,
    -1, 3,-3, 1,  -1, 3,-1,-3,  -1, 3,-1,-1,  -1, 3,-1, 1,  -1, 3,-1, 3,  -1, 3, 1,-3,  -1, 3, 1,-1,  -1, 3, 1, 1,
    -1, 3, 1, 3,  -1, 3, 3,-1,  -1, 3, 3, 1
};

DI unsigned short f2bf(float f) {  // f32 -> bf16 bits, round-to-nearest-even
  unsigned int u = __float_as_uint(f);
  u += 0x7fffu + ((u >> 16) & 1u);
  return (unsigned short)(u >> 16);
}

// Fused prep + repack (one dispatch).
// Blocks 0..511: Xa = scaled input, fragment-linear Xa[k>>5][m][(k>>3)&3][8].
// Blocks 512..639: Qidxs -> Qp u16 [B4=k>>5][n][j=(k>>3)&3] via LDS transpose.
__global__ __launch_bounds__(256) void prep_kernel(
    const float* __restrict__ inp, const float* __restrict__ sw,
    const float* __restrict__ qs, const int* __restrict__ qidx,
    unsigned short* __restrict__ xa, unsigned short* __restrict__ qp) {
  __shared__ unsigned short lw[16384];     // 32 KB (repack blocks only)
  const int t = threadIdx.x;

  if (blockIdx.x < 512) {                  // ---- prep part
    int i  = blockIdx.x * 256 + t;         // 16B slot id, 131072 total
    int j  = i & 3;
    int m  = (i >> 2) & 255;
    int kb = i >> 10;
    const float* ip = inp + (size_t)m * INF + kb * 32 + j * 8;
    float4 f0 = *reinterpret_cast<const float4*>(ip);
    float4 f1 = *reinterpret_cast<const float4*>(ip + 4);
    const float* sp = sw + kb * 32 + j * 8;
    float4 s0 = *reinterpret_cast<const float4*>(sp);
    float4 s1 = *reinterpret_cast<const float4*>(sp + 4);
    int g = kb * 8 + j * 2;
    float q0 = qs[g], q1 = qs[g + 1];
    union { unsigned short u[8]; uint4 v; } o;
    o.u[0] = f2bf(f0.x * s0.x * q0); o.u[1] = f2bf(f0.y * s0.y * q0);
    o.u[2] = f2bf(f0.z * s0.z * q0); o.u[3] = f2bf(f0.w * s0.w * q0);
    o.u[4] = f2bf(f1.x * s1.x * q1); o.u[5] = f2bf(f1.y * s1.y * q1);
    o.u[6] = f2bf(f1.z * s1.z * q1); o.u[7] = f2bf(f1.w * s1.w * q1);
    reinterpret_cast<uint4*>(xa)[i] = o.v;
    return;
  }

  // ---- repack part (r6 kernel, verified)
  const int n0 = (blockIdx.x - 512) * 32;
  char* lwb = reinterpret_cast<char*>(lw);
  const int b4w   = t >> 1;
  const int cbase = b4w * 256 + ((2 * t) & 3) * 2;
  const int xk    = (b4w & 31) << 3;
  for (int r = 0; r < 32; ++r) {
    int4 v = *reinterpret_cast<const int4*>(
        qidx + (size_t)(n0 + r) * NGRP + t * 4);
    unsigned p01 = (v.x & 255) | ((v.y & 255) << 8) |
                   ((v.z & 255) << 16) | ((unsigned)(v.w & 255) << 24);
    *reinterpret_cast<unsigned*>(lwb + cbase + ((r * 8) ^ xk)) = p01;
  }
  __syncthreads();
  for (int it = 0; it < 16; ++it) {
    int b4 = it * 8 + (t >> 5);
    int n  = t & 31;
    unsigned long long v = *reinterpret_cast<const unsigned long long*>(
        lwb + b4 * 256 + ((n * 8) ^ ((b4 & 31) << 3)));
    *reinterpret_cast<unsigned long long*>(
        reinterpret_cast<char*>(qp) + (size_t)b4 * 32768 +
        (size_t)(n0 + n) * 8) = v;
  }
}

// ---------------- staged-W fused dequant-GEMM (r13 upgraded) ---------------
// Grid 256 = 2 mt x 128 ns. Block 1024 thr / 16 waves = 2 mh(64m) x 8 kq
// (512k each); block tile 128m x 32n, full K in-block. Wave tile 64m x 32n
// halves B-read volume per MFMA. W step-tiles use conflict-free layout
// [k8-block(4)][n(32)][16B] (no swizzle needed: staging writes and compute
// reads both sweep banks linearly). lgkmcnt-only barriers; q for all 16
// steps preloaded. Epilogue: 3-stage LDS tree over the 8 kq partials.

#define MM(A, B, C) C = __builtin_amdgcn_mfma_f32_16x16x32_bf16(A, B, C, 0, 0, 0)
#define LD8(p) (*reinterpret_cast<const bf16x8*>(p))

#define BAR() do { \
    asm volatile("s_waitcnt lgkmcnt(0)\n\ts_barrier" ::: "memory"); \
    __builtin_amdgcn_sched_barrier(0); } while (0)

#define STG(QV, BUF) do { \
    ulonglong2 w_; \
    w_.x = tbl[(QV) & 255]; w_.y = tbl[(QV) >> 8]; \
    *reinterpret_cast<ulonglong2*>(wsm + wbase + (BUF) + wslot) = w_; } while (0)

#define AL(AB, T) do { \
    AB##_0 = LD8(axb + (size_t)(T) * 16384 +    0); \
    AB##_1 = LD8(axb + (size_t)(T) * 16384 + 1024); \
    AB##_2 = LD8(axb + (size_t)(T) * 16384 + 2048); \
    AB##_3 = LD8(axb + (size_t)(T) * 16384 + 3072); } while (0)

#define CMP(AB, BUFOFF) do { \
    const char* wp_ = wsm + kqW + (BUFOFF); \
    bf16x8 b0 = LD8(wp_ + rb0); \
    bf16x8 b1 = LD8(wp_ + rb1); \
    MM(AB##_0, b0, c00); MM(AB##_0, b1, c01); \
    MM(AB##_1, b0, c10); MM(AB##_1, b1, c11); \
    MM(AB##_2, b0, c20); MM(AB##_2, b1, c21); \
    MM(AB##_3, b0, c30); MM(AB##_3, b1, c31); } while (0)

#define STEPA(T, QN) do { \
    AL(AO, (T) + 1); STG(QN, (((T) + 1) & 1) * 2048); \
    CMP(AE, ((T) & 1) * 2048); BAR(); } while (0)
#define STEPB(T, QN) do { \
    AL(AE, (T) + 1); STG(QN, (((T) + 1) & 1) * 2048); \
    CMP(AO, ((T) & 1) * 2048); BAR(); } while (0)

__global__ __launch_bounds__(1024, 4) void gemm_kernel(
    const unsigned short* __restrict__ xa, const unsigned short* __restrict__ qp,
    float* __restrict__ out) {
  __shared__ float red[8][64 * 36];              // 73.7 KB, aliased regions
  unsigned long long* tbl =
      reinterpret_cast<unsigned long long*>(&red[0][0]);          // 2 KB
  char* wsm = reinterpret_cast<char*>(&red[0][0]) + 2048;         // 32 KB W

  const int tid  = threadIdx.x;             // 0..1023
  const int lane = tid & 63;
  const int wave = tid >> 6;                // 0..15
  const int mh   = wave >> 3;               // m half (64 rows)
  const int kq   = wave & 7;                // k eighth (512 k)
  const int l15  = lane & 15, l4 = lane >> 4;

  const int bid = blockIdx.x;               // 0..255
  const int ns  = bid & 127;                // n-strip; mt-partner on same XCD
  const int mt  = bid >> 7;
  const int n0  = ns * 32;
  const int m0  = mt * 128 + mh * 64;

  // ---- staging mapping: thread -> (kq tile kqs, n-row qn, k8-block j2)
  const int kqs = tid >> 7;                 // 0..7
  const int qn  = tid & 31;                 // 0..31
  const int j2  = (tid >> 5) & 3;           // 0..3
  const unsigned wbase = (unsigned)(kqs * 4096);
  const unsigned wslot = (unsigned)(j2 * 512 + qn * 16);   // [k8][n][16B]

  // ---- preload all 16 steps' packed q (one u16 = one k8-block of a row)
  const char* qpb = reinterpret_cast<const char*>(qp) +
      (size_t)(kqs * 16) * 32768 + (size_t)(n0 + qn) * 8 + j2 * 2;
#define QLD(K) ((unsigned)*reinterpret_cast<const unsigned short*>(qpb + (size_t)(K) * 32768))
  const unsigned Qs0 = QLD(0),  Qs1 = QLD(1),  Qs2 = QLD(2),  Qs3 = QLD(3);
  const unsigned Qs4 = QLD(4),  Qs5 = QLD(5),  Qs6 = QLD(6),  Qs7 = QLD(7);
  const unsigned Qs8 = QLD(8),  Qs9 = QLD(9),  Qsa = QLD(10), Qsb = QLD(11);
  const unsigned Qsc = QLD(12), Qsd = QLD(13), Qse = QLD(14), Qsf = QLD(15);
#undef QLD

  // ---- compute-side bases
  const char* axb = reinterpret_cast<const char*>(xa) +
      (size_t)(kq * 16) * 16384 + (size_t)(m0 + l15) * 64 + l4 * 16;
  const unsigned kqW = (unsigned)(kq * 4096);
  const unsigned rb0 = (unsigned)(l4 * 512 + l15 * 16);   // n-frag 0
  const unsigned rb1 = rb0 + 256;                         // n-frag 1 (+16 rows)

  bf16x8 AE_0, AE_1, AE_2, AE_3, AO_0, AO_1, AO_2, AO_3;
  f32x4  c00 = {}, c01 = {}, c10 = {}, c11 = {};
  f32x4  c20 = {}, c21 = {}, c30 = {}, c31 = {};

  AL(AE, 0);                                // in flight before tbl build

  // ---- signed codebook table: tbl[i] = 4 packed bf16, tbl[i+128] = -tbl[i]
  if (tid < 256) {
    int r = tid & 127, sg = tid >> 7;
    unsigned long long v = 0;
#pragma unroll
    for (int j = 0; j < 4; ++j) {
      float f = (float)D4_I8[r * 4 + j] * 0.5f;
      unsigned int b = __float_as_uint(f) ^ (sg ? 0x80000000u : 0u);
      v |= (unsigned long long)(b >> 16) << (16 * j);
    }
    tbl[tid] = v;
  }
  BAR();                                    // tbl ready
  STG(Qs0, 0);                              // stage step 0 into buf 0
  BAR();                                    // buf 0 ready

  // ---- 16 k-steps (32k each), lgkmcnt-only barrier per step
  STEPA(0,  Qs1); STEPB(1,  Qs2); STEPA(2,  Qs3); STEPB(3,  Qs4);
  STEPA(4,  Qs5); STEPB(5,  Qs6); STEPA(6,  Qs7); STEPB(7,  Qs8);
  STEPA(8,  Qs9); STEPB(9,  Qsa); STEPA(10, Qsb); STEPB(11, Qsc);
  STEPA(12, Qsd); STEPB(13, Qse); STEPA(14, Qsf);
  CMP(AO, 2048);                            // step 15 (no prefetch)
  BAR();                                    // W/tbl dead -> planes may alias

  // ---- 3-stage tree over 8 kq partials (planes alias tbl+W region)
#define PWR(PL) do { float* pl = (PL); \
    PW1(c00, 0, 0); PW1(c01, 0, 1); PW1(c10, 1, 0); PW1(c11, 1, 1); \
    PW1(c20, 2, 0); PW1(c21, 2, 1); PW1(c30, 3, 0); PW1(c31, 3, 1); } while (0)
#define PW1(C, MI, NI) do { \
    pl[((MI) * 16 + l4 * 4 + 0) * 36 + (NI) * 16 + l15] = C[0]; \
    pl[((MI) * 16 + l4 * 4 + 1) * 36 + (NI) * 16 + l15] = C[1]; \
    pl[((MI) * 16 + l4 * 4 + 2) * 36 + (NI) * 16 + l15] = C[2]; \
    pl[((MI) * 16 + l4 * 4 + 3) * 36 + (NI) * 16 + l15] = C[3]; } while (0)
#define PRD(PL) do { const float* pl = (PL); \
    PR1(c00, 0, 0); PR1(c01, 0, 1); PR1(c10, 1, 0); PR1(c11, 1, 1); \
    PR1(c20, 2, 0); PR1(c21, 2, 1); PR1(c30, 3, 0); PR1(c31, 3, 1); } while (0)
#define PR1(C, MI, NI) do { \
    C[0] += pl[((MI) * 16 + l4 * 4 + 0) * 36 + (NI) * 16 + l15]; \
    C[1] += pl[((MI) * 16 + l4 * 4 + 1) * 36 + (NI) * 16 + l15]; \
    C[2] += pl[((MI) * 16 + l4 * 4 + 2) * 36 + (NI) * 16 + l15]; \
    C[3] += pl[((MI) * 16 + l4 * 4 + 3) * 36 + (NI) * 16 + l15]; } while (0)

  if (kq >= 4) PWR(&red[mh * 4 + kq - 4][0]);
  BAR();
  if (kq < 4)  PRD(&red[mh * 4 + kq][0]);
  BAR();
  if (kq == 2 || kq == 3) PWR(&red[mh * 4 + kq - 2][0]);
  BAR();
  if (kq < 2)  PRD(&red[mh * 4 + kq][0]);
  BAR();
  if (kq == 1) PWR(&red[mh * 4][0]);
  BAR();
  if (kq == 0) {
    PRD(&red[mh * 4][0]);
    float* ob = out + (size_t)(m0 + l4 * 4) * MOUT + n0 + l15;
#define STO(C, MI, NI) do { \
    ob[(size_t)((MI) * 16 + 0) * MOUT + (NI) * 16] = C[0]; \
    ob[(size_t)((MI) * 16 + 1) * MOUT + (NI) * 16] = C[1]; \
    ob[(size_t)((MI) * 16 + 2) * MOUT + (NI) * 16] = C[2]; \
    ob[(size_t)((MI) * 16 + 3) * MOUT + (NI) * 16] = C[3]; } while (0)
    STO(c00, 0, 0); STO(c01, 0, 1); STO(c10, 1, 0); STO(c11, 1, 1);
    STO(c20, 2, 0); STO(c21, 2, 1); STO(c30, 3, 0); STO(c31, 3, 1);
#undef STO
  }
#undef PWR
#undef PW1
#undef PRD
#undef PR1
}

extern "C" void kernel_launch(void* const* d_in, const int* in_sizes, int n_in,
                              void* d_out, int out_size, void* d_ws, size_t ws_size,
                              hipStream_t stream) {
  const float* inp = (const float*)d_in[0];
  const float* sw  = (const float*)d_in[1];
  const float* qs  = (const float*)d_in[2];
  const int*   qi  = (const int*)d_in[3];
  float* out = (float*)d_out;
  unsigned short* xa = (unsigned short*)d_ws;                       // 2 MB
  unsigned short* qp = (unsigned short*)((char*)d_ws + (4 << 20));  // 4 MB

  prep_kernel<<<640, 256, 0, stream>>>(inp, sw, qs, qi, xa, qp);
  gemm_kernel<<<256, 1024, 0, stream>>>(xa, qp, out);
}

// Round 15
// 29.376 us; speedup vs baseline: 1.0602x; 1.0602x over previous
//
#include <hip/hip_runtime.h>

#define DI __device__ __forceinline__

constexpr int BATCH = 256;
constexpr int INF   = 4096;   // in_features
constexpr int NGRP  = 1024;   // INF/4
constexpr int MOUT  = 4096;   // out_features

using bf16x8 = __attribute__((ext_vector_type(8))) short;
using f32x4  = __attribute__((ext_vector_type(4))) float;

// D4 half-codebook, stored as 2x the actual values (int8); actual = v * 0.5
__device__ __constant__ signed char D4_I8[512] = {
     0, 0, 0, 0,  -4, 0, 0, 0,  -2,-2,-2,-2,  -2,-2,-2, 0,  -2,-2,-2, 2,  -2,-2, 0,-2,  -2,-2, 0, 0,  -2,-2, 0, 2,
    -2,-2, 2,-2,  -2,-2, 2, 0,  -2,-2, 2, 2,  -2, 0,-2,-2,  -2, 0,-2, 0,  -2, 0,-2, 2,  -2, 0, 0,-2,  -2, 0, 0, 0,
    -2, 0, 0, 2,  -2, 0, 2,-2,  -2, 0, 2, 0,  -2, 0, 2, 2,  -2, 2,-2,-2,  -2, 2,-2, 0,  -2, 2,-2, 2,  -2, 2, 0,-2,
    -2, 2, 0, 0,  -2, 2, 0, 2,  -2, 2, 2,-2,  -2, 2, 2, 0,  -2, 2, 2, 2,   0,-4, 0, 0,   0,-2,-2,-2,   0,-2,-2, 0,
     0,-2,-2, 2,   0,-2, 0,-2,   0,-2, 0, 0,   0,-2, 0, 2,   0,-2, 2,-2,   0,-2, 2, 0,   0,-2, 2, 2,   0, 0,-4, 0,
     0, 0,-2,-2,   0, 0,-2, 0,   0, 0,-2, 2,   0, 0, 0,-4,   0, 0, 0,-2,
    -3,-1,-3,-1,  -3,-1,-3, 1,  -3,-1,-1,-3,  -3,-1,-1,-1,  -3,-1,-1, 1,  -3,-1,-1, 3,  -3,-1, 1,-3,  -3,-1, 1,-1,
    -3,-1, 1, 1,  -3,-1, 1, 3,  -3,-1, 3,-1,  -3,-1, 3, 1,  -3, 1,-3,-1,  -3, 1,-3, 1,  -3, 1,-1,-3,  -3, 1,-1,-1,
    -3, 1,-1, 1,  -3, 1,-1, 3,  -3, 1, 1,-3,  -3, 1, 1,-1,  -3, 1, 1, 1,  -3, 1, 1, 3,  -3, 1, 3,-1,  -3, 1, 3, 1,
    -3, 3,-1,-1,  -3, 3, 1,-1,  -3, 3, 1, 1,  -1,-3,-3,-1,  -1,-3,-3, 1,  -1,-3,-1,-3,  -1,-3,-1,-1,  -1,-3,-1, 1,
    -1,-3,-1, 3,  -1,-3, 1,-3,  -1,-3, 1,-1,  -1,-3, 1, 1,  -1,-3, 1, 3,  -1,-3, 3,-1,  -1,-3, 3, 1,  -1,-1,-3,-3,
    -1,-1,-3,-1,  -1,-1,-3, 1,  -1,-1,-3, 3,  -1,-1,-1,-3,  -1,-1,-1,-1,  -1,-1,-1, 1,  -1,-1,-1, 3,  -1,-1, 1,-3,
    -1,-1, 1,-1,  -1,-1, 1, 1,  -1,-1, 1, 3,  -1,-1, 3,-3,  -1,-1, 3,-1,  -1,-1, 3, 1,  -1,-1, 3, 3,  -1, 1,-3,-3,
    -1, 1,-3,-1,  -1, 1,-3, 1,  -1, 1,-3, 3,  -1, 1,-1,-3,  -1, 1,-1,-1,  -1, 1,-1, 1,  -1, 1,-1, 3,  -1, 1, 1,-3,
    -1, 1, 1,-1,  -1, 1, 1, 1,  -1, 1, 1, 3,  -1, 1, 3,-3,  -1, 1, 3,-1,  -1, 1, 3, 1,  -1, 1, 3, 3,  -1, 3,-3,-1,
    -1, 3,-3, 1,  -1, 3,-1,-3,  -1, 3,-1,-1,  -1, 3,-1, 1,  -1, 3,-1, 3,  -1, 3, 1,-3,  -1, 3, 1,-1,  -1, 3, 1, 1,
    -1, 3, 1, 3,  -1, 3, 3,-1,  -1, 3, 3, 1
};

DI unsigned short f2bf(float f) {  // f32 -> bf16 bits, round-to-nearest-even
  unsigned int u = __float_as_uint(f);
  u += 0x7fffu + ((u >> 16) & 1u);
  return (unsigned short)(u >> 16);
}

// Fused prep + repack (one dispatch).
// Blocks 0..511: Xa = scaled input, fragment-linear Xa[k>>5][m][(k>>3)&3][8].
// Blocks 512..639: Qidxs -> Qp u16 [B4=k>>5][n][j=(k>>3)&3] via LDS transpose.
__global__ __launch_bounds__(256) void prep_kernel(
    const float* __restrict__ inp, const float* __restrict__ sw,
    const float* __restrict__ qs, const int* __restrict__ qidx,
    unsigned short* __restrict__ xa, unsigned short* __restrict__ qp) {
  __shared__ unsigned short lw[16384];     // 32 KB (repack blocks only)
  const int t = threadIdx.x;

  if (blockIdx.x < 512) {                  // ---- prep part
    int i  = blockIdx.x * 256 + t;         // 16B slot id, 131072 total
    int j  = i & 3;
    int m  = (i >> 2) & 255;
    int kb = i >> 10;
    const float* ip = inp + (size_t)m * INF + kb * 32 + j * 8;
    float4 f0 = *reinterpret_cast<const float4*>(ip);
    float4 f1 = *reinterpret_cast<const float4*>(ip + 4);
    const float* sp = sw + kb * 32 + j * 8;
    float4 s0 = *reinterpret_cast<const float4*>(sp);
    float4 s1 = *reinterpret_cast<const float4*>(sp + 4);
    int g = kb * 8 + j * 2;
    float q0 = qs[g], q1 = qs[g + 1];
    union { unsigned short u[8]; uint4 v; } o;
    o.u[0] = f2bf(f0.x * s0.x * q0); o.u[1] = f2bf(f0.y * s0.y * q0);
    o.u[2] = f2bf(f0.z * s0.z * q0); o.u[3] = f2bf(f0.w * s0.w * q0);
    o.u[4] = f2bf(f1.x * s1.x * q1); o.u[5] = f2bf(f1.y * s1.y * q1);
    o.u[6] = f2bf(f1.z * s1.z * q1); o.u[7] = f2bf(f1.w * s1.w * q1);
    reinterpret_cast<uint4*>(xa)[i] = o.v;
    return;
  }

  // ---- repack part (r6 kernel, verified)
  const int n0 = (blockIdx.x - 512) * 32;
  char* lwb = reinterpret_cast<char*>(lw);
  const int b4w   = t >> 1;
  const int cbase = b4w * 256 + ((2 * t) & 3) * 2;
  const int xk    = (b4w & 31) << 3;
  for (int r = 0; r < 32; ++r) {
    int4 v = *reinterpret_cast<const int4*>(
        qidx + (size_t)(n0 + r) * NGRP + t * 4);
    unsigned p01 = (v.x & 255) | ((v.y & 255) << 8) |
                   ((v.z & 255) << 16) | ((unsigned)(v.w & 255) << 24);
    *reinterpret_cast<unsigned*>(lwb + cbase + ((r * 8) ^ xk)) = p01;
  }
  __syncthreads();
  for (int it = 0; it < 16; ++it) {
    int b4 = it * 8 + (t >> 5);
    int n  = t & 31;
    unsigned long long v = *reinterpret_cast<const unsigned long long*>(
        lwb + b4 * 256 + ((n * 8) ^ ((b4 & 31) << 3)));
    *reinterpret_cast<unsigned long long*>(
        reinterpret_cast<char*>(qp) + (size_t)b4 * 32768 +
        (size_t)(n0 + n) * 8) = v;
  }
}

// ---------------- staged-W fused dequant-GEMM (r13 base + step reorder) ----
// Grid 256 = 2 mt x 128 ns. Block 1024 thr / 16 waves = 4 mh x 4 kq; block
// tile 128m x 32n, full K in-block (kq = 1024k each). Step order is
// B-reads -> staging(lookups+write) -> A-loads -> MFMAs: the MFMA wait
// becomes a counted lgkmcnt that EXCLUDES the random-conflict table
// lookups (in-order LDS completion would otherwise gate MFMAs on them).
// lgkmcnt-only barriers (A-loads fly across steps). q preloaded (16 regs).

#define MM(A, B, C) C = __builtin_amdgcn_mfma_f32_16x16x32_bf16(A, B, C, 0, 0, 0)
#define LD8(p) (*reinterpret_cast<const bf16x8*>(p))

#define BAR() do { \
    asm volatile("s_waitcnt lgkmcnt(0)\n\ts_barrier" ::: "memory"); \
    __builtin_amdgcn_sched_barrier(0); } while (0)

#define STG(QV, BUF) do { \
    ulonglong2 w_; \
    w_.x = tbl[(QV) & 255]; w_.y = tbl[(QV) >> 8]; \
    *reinterpret_cast<ulonglong2*>(wsm + wbase + (BUF) + wslot) = w_; } while (0)

#define AL(AB, T) do { \
    AB##_0 = LD8(axb + (size_t)(T) * 32768 +     0); \
    AB##_1 = LD8(axb + (size_t)(T) * 32768 +  1024); \
    AB##_2 = LD8(axb + (size_t)(T) * 32768 + 16384); \
    AB##_3 = LD8(axb + (size_t)(T) * 32768 + 17408); } while (0)

// One k-step: B-reads issued FIRST (data ready since last barrier), then
// next-step staging + A prefetch, then the MFMA cluster (counted lgkm wait
// covers only the 4 B-reads), then the barrier.
#define STEPA(T, QN) do { \
    const char* wp_ = wsm + kqW + ((T) & 1) * 4096; \
    bf16x8 b00 = LD8(wp_ + rb00); \
    bf16x8 b01 = LD8(wp_ + rb00 + 2048); \
    bf16x8 b10 = LD8(wp_ + rb10); \
    bf16x8 b11 = LD8(wp_ + rb10 + 2048); \
    STG(QN, (((T) + 1) & 1) * 4096); \
    AL(AO, (T) + 1); \
    MM(AE_0, b00, c00); MM(AE_0, b01, c01); \
    MM(AE_1, b00, c10); MM(AE_1, b01, c11); \
    MM(AE_2, b10, c00); MM(AE_2, b11, c01); \
    MM(AE_3, b10, c10); MM(AE_3, b11, c11); \
    BAR(); } while (0)
#define STEPB(T, QN) do { \
    const char* wp_ = wsm + kqW + ((T) & 1) * 4096; \
    bf16x8 b00 = LD8(wp_ + rb00); \
    bf16x8 b01 = LD8(wp_ + rb00 + 2048); \
    bf16x8 b10 = LD8(wp_ + rb10); \
    bf16x8 b11 = LD8(wp_ + rb10 + 2048); \
    STG(QN, (((T) + 1) & 1) * 4096); \
    AL(AE, (T) + 1); \
    MM(AO_0, b00, c00); MM(AO_0, b01, c01); \
    MM(AO_1, b00, c10); MM(AO_1, b01, c11); \
    MM(AO_2, b10, c00); MM(AO_2, b11, c01); \
    MM(AO_3, b10, c10); MM(AO_3, b11, c11); \
    BAR(); } while (0)

__global__ __launch_bounds__(1024, 4) void gemm_kernel(
    const unsigned short* __restrict__ xa, const unsigned short* __restrict__ qp,
    float* __restrict__ out) {
  __shared__ unsigned long long tbl[256];   // 2 KB sign-folded bf16x4 codebook
  __shared__ float red[12][1152];           // 55.3 KB; W region aliases front
  char* wsm = reinterpret_cast<char*>(red); // W: [kq(4)][buf(2)][4 KB] = 32 KB

  const int tid  = threadIdx.x;             // 0..1023
  const int lane = tid & 63;
  const int wave = tid >> 6;                // 0..15
  const int mh   = wave >> 2;               // m sub-tile (32 rows)
  const int kq   = wave & 3;                // k quarter (1024 k)
  const int l15  = lane & 15, l4 = lane >> 4;

  const int bid = blockIdx.x;               // 0..255
  const int ns  = bid & 127;                // n-strip; mt-partner on same XCD
  const int mt  = bid >> 7;
  const int n0  = ns * 32;
  const int m0  = mt * 128 + mh * 32;

  // ---- staging mapping: thread -> (tile kqs, n-row qn, oct-pair j2)
  const int kqs = tid >> 8;                 // 0..3
  const int qn  = (tid & 255) >> 3;         // 0..31
  const int j2  = tid & 7;                  // (j2>>2) = B4 half, (j2&3) = j
  const unsigned wbase = (unsigned)(kqs * 8192);
  const unsigned wslot =
      ((unsigned)(qn * 128 + j2 * 16)) ^ ((unsigned)(qn & 7) << 4);

  // ---- preload all 16 steps' packed q (coalesced 64B rows of Qp)
  const char* qpb = reinterpret_cast<const char*>(qp) +
      (size_t)(kqs * 32 + (j2 >> 2)) * 32768 + (size_t)(n0 + qn) * 8 +
      (j2 & 3) * 2;
#define QLD(K) ((unsigned)*reinterpret_cast<const unsigned short*>(qpb + (size_t)(K) * 65536))
  const unsigned Qs0 = QLD(0),  Qs1 = QLD(1),  Qs2 = QLD(2),  Qs3 = QLD(3);
  const unsigned Qs4 = QLD(4),  Qs5 = QLD(5),  Qs6 = QLD(6),  Qs7 = QLD(7);
  const unsigned Qs8 = QLD(8),  Qs9 = QLD(9),  Qsa = QLD(10), Qsb = QLD(11);
  const unsigned Qsc = QLD(12), Qsd = QLD(13), Qse = QLD(14), Qsf = QLD(15);
#undef QLD

  // ---- compute-side bases
  const char* axb = reinterpret_cast<const char*>(xa) +
      (size_t)(kq * 32) * 16384 + (size_t)(m0 + l15) * 64 + l4 * 16;
  const unsigned swzB = (unsigned)(l15 & 7) << 4;
  const unsigned kqW  = (unsigned)(kq * 8192);
  const unsigned rb00 = ((unsigned)(l15 * 128 + l4 * 16)) ^ swzB;
  const unsigned rb10 = ((unsigned)(l15 * 128 + 64 + l4 * 16)) ^ swzB;

  bf16x8 AE_0, AE_1, AE_2, AE_3, AO_0, AO_1, AO_2, AO_3;
  f32x4  c00 = {}, c01 = {}, c10 = {}, c11 = {};

  AL(AE, 0);                                // in flight before tbl build

  // ---- signed codebook table: tbl[i] = 4 packed bf16, tbl[i+128] = -tbl[i]
  if (tid < 256) {
    int r = tid & 127, sg = tid >> 7;
    unsigned long long v = 0;
#pragma unroll
    for (int j = 0; j < 4; ++j) {
      float f = (float)D4_I8[r * 4 + j] * 0.5f;
      unsigned int b = __float_as_uint(f) ^ (sg ? 0x80000000u : 0u);
      v |= (unsigned long long)(b >> 16) << (16 * j);
    }
    tbl[tid] = v;
  }
  BAR();                                    // tbl ready
  STG(Qs0, 0);                              // stage step 0 into buf 0
  BAR();                                    // buf 0 ready

  // ---- 16 k-steps (64k each), lgkmcnt-only barrier per step
  STEPA(0,  Qs1); STEPB(1,  Qs2); STEPA(2,  Qs3); STEPB(3,  Qs4);
  STEPA(4,  Qs5); STEPB(5,  Qs6); STEPA(6,  Qs7); STEPB(7,  Qs8);
  STEPA(8,  Qs9); STEPB(9,  Qsa); STEPA(10, Qsb); STEPB(11, Qsc);
  STEPA(12, Qsd); STEPB(13, Qse); STEPA(14, Qsf);
  {                                         // step 15 (no prefetch)
    const char* wp_ = wsm + kqW + 4096;
    bf16x8 b00 = LD8(wp_ + rb00);
    bf16x8 b01 = LD8(wp_ + rb00 + 2048);
    bf16x8 b10 = LD8(wp_ + rb10);
    bf16x8 b11 = LD8(wp_ + rb10 + 2048);
    MM(AO_0, b00, c00); MM(AO_0, b01, c01);
    MM(AO_1, b00, c10); MM(AO_1, b01, c11);
    MM(AO_2, b10, c00); MM(AO_2, b11, c01);
    MM(AO_3, b10, c10); MM(AO_3, b11, c11);
  }
  BAR();                                    // all W reads done -> planes may alias

  // ---- kq-reduction through LDS planes (alias W region), store once
#define PWR(C, MI, NI) do { \
    pl[((MI) * 16 + l4 * 4 + 0) * 36 + (NI) * 16 + l15] = C[0]; \
    pl[((MI) * 16 + l4 * 4 + 1) * 36 + (NI) * 16 + l15] = C[1]; \
    pl[((MI) * 16 + l4 * 4 + 2) * 36 + (NI) * 16 + l15] = C[2]; \
    pl[((MI) * 16 + l4 * 4 + 3) * 36 + (NI) * 16 + l15] = C[3]; } while (0)
#define PRD(C, MI, NI) do { \
    C[0] += pl[((MI) * 16 + l4 * 4 + 0) * 36 + (NI) * 16 + l15]; \
    C[1] += pl[((MI) * 16 + l4 * 4 + 1) * 36 + (NI) * 16 + l15]; \
    C[2] += pl[((MI) * 16 + l4 * 4 + 2) * 36 + (NI) * 16 + l15]; \
    C[3] += pl[((MI) * 16 + l4 * 4 + 3) * 36 + (NI) * 16 + l15]; } while (0)

  if (kq) {
    float* pl = &red[mh * 3 + kq - 1][0];
    PWR(c00, 0, 0); PWR(c01, 0, 1); PWR(c10, 1, 0); PWR(c11, 1, 1);
  }
  __syncthreads();
  if (kq == 0) {
#pragma unroll
    for (int p = 0; p < 3; ++p) {
      const float* pl = &red[mh * 3 + p][0];
      PRD(c00, 0, 0); PRD(c01, 0, 1); PRD(c10, 1, 0); PRD(c11, 1, 1);
    }
    float* ob = out + (size_t)(m0 + l4 * 4) * MOUT + n0 + l15;
#define STO(C, MI, NI) do { \
    ob[(size_t)((MI) * 16 + 0) * MOUT + (NI) * 16] = C[0]; \
    ob[(size_t)((MI) * 16 + 1) * MOUT + (NI) * 16] = C[1]; \
    ob[(size_t)((MI) * 16 + 2) * MOUT + (NI) * 16] = C[2]; \
    ob[(size_t)((MI) * 16 + 3) * MOUT + (NI) * 16] = C[3]; } while (0)
    STO(c00, 0, 0); STO(c01, 0, 1); STO(c10, 1, 0); STO(c11, 1, 1);
#undef STO
  }
#undef PWR
#undef PRD
}

extern "C" void kernel_launch(void* const* d_in, const int* in_sizes, int n_in,
                              void* d_out, int out_size, void* d_ws, size_t ws_size,
                              hipStream_t stream) {
  const float* inp = (const float*)d_in[0];
  const float* sw  = (const float*)d_in[1];
  const float* qs  = (const float*)d_in[2];
  const int*   qi  = (const int*)d_in[3];
  float* out = (float*)d_out;
  unsigned short* xa = (unsigned short*)d_ws;                       // 2 MB
  unsigned short* qp = (unsigned short*)((char*)d_ws + (4 << 20));  // 4 MB

  prep_kernel<<<640, 256, 0, stream>>>(inp, sw, qs, qi, xa, qp);
  gemm_kernel<<<256, 1024, 0, stream>>>(xa, qp, out);
}